// Round 7
// baseline (56.801 us; speedup 1.0000x reference)
//
#include <hip/hip_runtime.h>
#include <hip/hip_bf16.h>

// Depthwise 4x4 binomial blur + stride-2 downsample, separable [1,3,3,1] x2, /64.
// Input (B*C, 256, 256) fp32 -> output (B*C, 128, 128) fp32, pad=1.
//
// Barrier-free, LDS-free streaming. One wave produces SIXTEEN output rows
// (16s..16s+15) in 8 phases with a 2-row h-carry chain: each phase loads 4 new
// input rows (wave-wide float4 = whole 256-float row each), emits 2 output
// rows. Each input row is loaded exactly once per wave: 34 loads / 32 ideal
// rows = 1.0625x issue amplification (vs 1.25x for row-quad waves).
// Horizontal [1,3,3,1] via 2 lane shuffles; edges branchless (clamp + mask);
// nontemporal stores keep the L3 input-resident.
// grid (2,1024) x 4 waves = 8192 waves = exactly 8 waves/SIMD residency at the
// __launch_bounds__(256, 8) VGPR cap (<=64) -> zero tail, uniform work.

#define IN_H 256
#define IN_W 256
#define OUT_H 128
#define OUT_W 128

__device__ __forceinline__ void hrow(const float* __restrict__ xp, int r,
                                     int lane, float& h0, float& h1) {
    const int rc  = min(max(r, 0), IN_H - 1);
    const float m = (r == rc) ? 1.0f : 0.0f;     // zero-pad mask (top/bottom)
    const float4 v = *(const float4*)(xp + (size_t)rc * IN_W + 4 * lane);
    float prev = __shfl_up(v.w, 1);              // x[4l-1]
    float next = __shfl_down(v.x, 1);            // x[4l+4]
    prev = (lane == 0)  ? 0.0f : prev;           // left zero-pad
    next = (lane == 63) ? 0.0f : next;           // right zero-pad
    h0 = m * (prev + 3.0f * v.x + 3.0f * v.y + v.z);
    h1 = m * (v.y + 3.0f * v.z + 3.0f * v.w + next);
}

__device__ __forceinline__ void nt_store2(float* p, float a, float b) {
    float2 o; o.x = a; o.y = b;
    __builtin_nontemporal_store(*(double*)&o, (double*)p);
}

__global__ __launch_bounds__(256, 8) void downsample_kernel(
    const float* __restrict__ x, float* __restrict__ y) {
    const int plane = blockIdx.y;
    const int s     = blockIdx.x * 4 + (threadIdx.x >> 6);  // strip idx 0..7
    const int lane  = threadIdx.x & 63;
    const float* __restrict__ xp = x + (size_t)plane * IN_H * IN_W;
    float* __restrict__ yp =
        y + (size_t)plane * OUT_H * OUT_W + (size_t)(16 * s) * OUT_W;
    const int rbase = 32 * s;
    const float sc = 1.0f / 64.0f;   // (1/8)*(1/8) applied once

    // carry: h-filtered rows (rbase + 4t - 1) and (rbase + 4t)
    float c[2][2], g[4][2];
    hrow(xp, rbase - 1, lane, c[0][0], c[0][1]);
    hrow(xp, rbase,     lane, c[1][0], c[1][1]);

    #pragma unroll
    for (int t = 0; t < 8; ++t) {
        #pragma unroll
        for (int k = 0; k < 4; ++k)
            hrow(xp, rbase + 4 * t + 1 + k, lane, g[k][0], g[k][1]);

        nt_store2(yp + (size_t)(2 * t) * OUT_W + 2 * lane,
                  (c[0][0] + 3.0f * c[1][0] + 3.0f * g[0][0] + g[1][0]) * sc,
                  (c[0][1] + 3.0f * c[1][1] + 3.0f * g[0][1] + g[1][1]) * sc);
        nt_store2(yp + (size_t)(2 * t + 1) * OUT_W + 2 * lane,
                  (g[0][0] + 3.0f * g[1][0] + 3.0f * g[2][0] + g[3][0]) * sc,
                  (g[0][1] + 3.0f * g[1][1] + 3.0f * g[2][1] + g[3][1]) * sc);

        c[0][0] = g[2][0]; c[0][1] = g[2][1];   // carry rows 4t+3, 4t+4
        c[1][0] = g[3][0]; c[1][1] = g[3][1];
    }
}

extern "C" void kernel_launch(void* const* d_in, const int* in_sizes, int n_in,
                              void* d_out, int out_size, void* d_ws, size_t ws_size,
                              hipStream_t stream) {
    (void)n_in; (void)d_ws; (void)ws_size; (void)out_size;
    const float* x = (const float*)d_in[0];
    float* y = (float*)d_out;
    const int planes = in_sizes[0] / (IN_H * IN_W);   // B*C = 1024
    dim3 grid(2, planes);     // 2 blocks x 4 waves = 8 strips x 16 rows = 128
    dim3 block(256);
    downsample_kernel<<<grid, block, 0, stream>>>(x, y);
}

// Round 8
// 53.051 us; speedup vs baseline: 1.0707x; 1.0707x over previous
//
#include <hip/hip_runtime.h>
#include <hip/hip_bf16.h>

// Depthwise 4x4 binomial blur + stride-2 downsample, separable [1,3,3,1] x2, /64.
// Input (B*C, 256, 256) fp32 -> output (B*C, 128, 128) fp32, pad=1.
//
// Barrier-free, LDS-free. One wave produces FOUR output rows (4q..4q+3),
// reading 10 input rows, EXPLICITLY SOFTWARE-PIPELINED:
//   issue loads rows 8q-1..8q+4  -> h-filter them
//   issue loads rows 8q+5..8q+8  (in flight during phase-1 compute/stores)
//   compute+store output rows 4q, 4q+1
//   h-filter the 4 landed rows, compute+store rows 4q+2, 4q+3
// Each input row is one wave-wide float4 load (64 lanes x 16 B = whole row);
// horizontal [1,3,3,1] via 2 lane shuffles; edges branchless (clamp + mask);
// nontemporal stores keep the L3 input-resident.
// __launch_bounds__(256, 8): <=64 VGPR, 8 waves/SIMD (peak live ~40 VGPR).

#define IN_H 256
#define IN_W 256
#define OUT_H 128
#define OUT_W 128

__device__ __forceinline__ float4 load_row(const float* __restrict__ xp, int r,
                                           int lane, float& m) {
    const int rc = min(max(r, 0), IN_H - 1);
    m = (r == rc) ? 1.0f : 0.0f;                 // zero-pad mask (top/bottom)
    return *(const float4*)(xp + (size_t)rc * IN_W + 4 * lane);
}

__device__ __forceinline__ void hfilt(float4 v, float m, int lane,
                                      float& h0, float& h1) {
    float prev = __shfl_up(v.w, 1);              // x[4l-1]
    float next = __shfl_down(v.x, 1);            // x[4l+4]
    prev = (lane == 0)  ? 0.0f : prev;           // left zero-pad
    next = (lane == 63) ? 0.0f : next;           // right zero-pad
    h0 = m * (prev + 3.0f * v.x + 3.0f * v.y + v.z);
    h1 = m * (v.y + 3.0f * v.z + 3.0f * v.w + next);
}

__device__ __forceinline__ void nt_store2(float* p, float a, float b) {
    float2 o; o.x = a; o.y = b;
    __builtin_nontemporal_store(*(double*)&o, (double*)p);
}

__global__ __launch_bounds__(256, 8) void downsample_kernel(
    const float* __restrict__ x, float* __restrict__ y) {
    const int plane = blockIdx.y;
    const int q     = blockIdx.x * 4 + (threadIdx.x >> 6);  // row-quad idx 0..31
    const int lane  = threadIdx.x & 63;
    const float* __restrict__ xp = x + (size_t)plane * IN_H * IN_W;
    float* __restrict__ yp =
        y + (size_t)plane * OUT_H * OUT_W + (size_t)(4 * q) * OUT_W + 2 * lane;
    const float s = 1.0f / 64.0f;   // (1/8)*(1/8) applied once

    // Issue phase-1 loads (rows 8q-1..8q+4).
    float m[10];
    float4 v[6];
    #pragma unroll
    for (int k = 0; k < 6; ++k)
        v[k] = load_row(xp, 8 * q - 1 + k, lane, m[k]);

    // H-filter phase 1 (consumes v as loads land).
    float h[6][2];
    #pragma unroll
    for (int k = 0; k < 6; ++k)
        hfilt(v[k], m[k], lane, h[k][0], h[k][1]);

    // Issue phase-2 loads (rows 8q+5..8q+8) BEFORE phase-1 stores.
    float4 w[4];
    #pragma unroll
    for (int k = 0; k < 4; ++k)
        w[k] = load_row(xp, 8 * q + 5 + k, lane, m[6 + k]);

    // Phase-1 outputs (rows 4q, 4q+1) — w loads in flight underneath.
    nt_store2(yp,
              (h[0][0] + 3.0f * h[1][0] + 3.0f * h[2][0] + h[3][0]) * s,
              (h[0][1] + 3.0f * h[1][1] + 3.0f * h[2][1] + h[3][1]) * s);
    nt_store2(yp + OUT_W,
              (h[2][0] + 3.0f * h[3][0] + 3.0f * h[4][0] + h[5][0]) * s,
              (h[2][1] + 3.0f * h[3][1] + 3.0f * h[4][1] + h[5][1]) * s);

    // H-filter phase 2, then outputs (rows 4q+2, 4q+3).
    float g[4][2];
    #pragma unroll
    for (int k = 0; k < 4; ++k)
        hfilt(w[k], m[6 + k], lane, g[k][0], g[k][1]);

    nt_store2(yp + 2 * OUT_W,
              (h[4][0] + 3.0f * h[5][0] + 3.0f * g[0][0] + g[1][0]) * s,
              (h[4][1] + 3.0f * h[5][1] + 3.0f * g[0][1] + g[1][1]) * s);
    nt_store2(yp + 3 * OUT_W,
              (g[0][0] + 3.0f * g[1][0] + 3.0f * g[2][0] + g[3][0]) * s,
              (g[0][1] + 3.0f * g[1][1] + 3.0f * g[2][1] + g[3][1]) * s);
}

extern "C" void kernel_launch(void* const* d_in, const int* in_sizes, int n_in,
                              void* d_out, int out_size, void* d_ws, size_t ws_size,
                              hipStream_t stream) {
    (void)n_in; (void)d_ws; (void)ws_size; (void)out_size;
    const float* x = (const float*)d_in[0];
    float* y = (float*)d_out;
    const int planes = in_sizes[0] / (IN_H * IN_W);   // B*C = 1024
    dim3 grid(8, planes);     // 8 blocks x 4 waves = 32 row-quads = 128 rows
    dim3 block(256);
    downsample_kernel<<<grid, block, 0, stream>>>(x, y);
}